// Round 9
// baseline (410.396 us; speedup 1.0000x reference)
//
#include <hip/hip_runtime.h>
#include <hip/hip_bf16.h>

#define NH 12
constexpr float SCALE = 0.17677669529663687f;  // 1/sqrt(32)
constexpr int TOKENS = 100352;

using f32x4  = __attribute__((ext_vector_type(4))) float;
using bf16x8 = __attribute__((ext_vector_type(8))) __bf16;

__device__ inline void gload_lds16(const void* g, void* l) {
  __builtin_amdgcn_global_load_lds(
      (const __attribute__((address_space(1))) void*)g,
      (__attribute__((address_space(3))) void*)l, 16, 0, 0);
}

__device__ inline bf16x8 cvt8(float4 a, float4 b) {
  bf16x8 o;
  o[0] = (__bf16)a.x; o[1] = (__bf16)a.y; o[2] = (__bf16)a.z; o[3] = (__bf16)a.w;
  o[4] = (__bf16)b.x; o[5] = (__bf16)b.y; o[6] = (__bf16)b.z; o[7] = (__bf16)b.w;
  return o;
}

#define MFMA(a, b, c) __builtin_amdgcn_mfma_f32_16x16x32_bf16(a, b, c, 0, 0, 0)

// ---------------- K0: weight bf16 conversion + transposed padded bias ----------
// biasTt layout: [12][64 col(j)][64 row(i)] fp32; j>=49 -> -1e30 (mask), i>=49 -> 0.
__global__ __launch_bounds__(256) void wa_prep(
    const float* __restrict__ qkv_w, const float* __restrict__ proj_w,
    const float* __restrict__ tbl,
    __bf16* __restrict__ qkv_w_bf, __bf16* __restrict__ proj_w_bf,
    float* __restrict__ biasTt) {
  int p = blockIdx.x * 256 + threadIdx.x;
  if (p < 442368) { qkv_w_bf[p] = (__bf16)qkv_w[p]; return; }
  p -= 442368;
  if (p < 147456) { proj_w_bf[p] = (__bf16)proj_w[p]; return; }
  p -= 147456;
  if (p >= 49152) return;
  int h = p >> 12, rem = p & 4095, j = rem >> 6, i = rem & 63;  // j=key col, i=query row
  float v;
  if (j >= 49) v = -1e30f;
  else if (i >= 49) v = 0.0f;
  else {
    int py = i / 7, px = i % 7, qy = j / 7, qx = j % 7;
    v = tbl[((py - qy + 6) * 13 + (px - qx + 6)) * NH + h];
  }
  biasTt[p] = v;
}

// ---------------- K1: QKV GEMM 64x128, BK=64, 6 blocks/CU ----------------
// LDS 24KB: As 8KB + Bs 16KB, epilogue Cs OVERLAYS Bs (dead after last MFMA,
// ordered by one extra barrier) -> 6 blocks/CU (24 waves, was 4/16 at 40KB).
// Grid 14112 XCD-grouped: the 9 nb-blocks of one mb land on one XCD (x
// HBM-read once, L2 re-reads). TLP hides stage latency (m114).
__global__ __launch_bounds__(256, 6) void wa_qkv(
    const float* __restrict__ x, const __bf16* __restrict__ wq,
    const float* __restrict__ qkv_b, __bf16* __restrict__ qkv) {
  __shared__ alignas(16) __bf16 smem[12288];   // 24KB
  __bf16* As = smem;          // [64 rows][8 chunks ^ (row&7)]  8KB
  __bf16* Bs = smem + 4096;   // [128 cols][8 chunks ^ (col&7)] 16KB
  __bf16* Cs = smem + 4096;   // overlays Bs (epilogue only)
  const int t = threadIdx.x, lane = t & 63, wv = t >> 6;
  const int lr = lane & 15, ls = lane >> 4;
  const int bid = blockIdx.x;
  const int q = bid / 72, rem = bid - q * 72;
  const int nb = rem >> 3, mb = q * 8 + (rem & 7);
  const int wr = wv >> 1, wc = wv & 1;   // wave tile: 32 rows x 64 cols
  f32x4 acc[2][4] = {};
  for (int kk = 0; kk < 6; ++kk) {
    if (kk) __syncthreads();
    // issue A fp32 loads (2 chunks/thread) + B gload_lds (4/thread)
    float4 a0[2], a1[2];
    int rowA[2], cA[2];
    #pragma unroll
    for (int j = 0; j < 2; ++j) {
      int p = j * 256 + t;
      rowA[j] = p >> 3; cA[j] = p & 7;
      const float* src = x + (size_t)(mb * 64 + rowA[j]) * 384 + kk * 64 + cA[j] * 8;
      a0[j] = *(const float4*)src;
      a1[j] = *(const float4*)(src + 4);
    }
    #pragma unroll
    for (int j = 0; j < 4; ++j) {
      int p = j * 256 + t;
      int c = p >> 3, sl = p & 7;
      gload_lds16(wq + (size_t)(nb * 128 + c) * 384 + kk * 64 + (sl ^ (c & 7)) * 8,
                  Bs + p * 8);
    }
    #pragma unroll
    for (int j = 0; j < 2; ++j) {
      int cw = cA[j] ^ (rowA[j] & 7);
      *(bf16x8*)(As + rowA[j] * 64 + cw * 8) = cvt8(a0[j], a1[j]);
    }
    __syncthreads();
    #pragma unroll
    for (int ks = 0; ks < 2; ++ks) {
      bf16x8 af[2], bfr[4];
      #pragma unroll
      for (int rt = 0; rt < 2; ++rt) {
        int row = wr * 32 + rt * 16 + lr;
        af[rt] = *(const bf16x8*)(As + row * 64 + (((ks * 4 + ls) ^ (row & 7)) * 8));
      }
      #pragma unroll
      for (int ct = 0; ct < 4; ++ct) {
        int c = wc * 64 + ct * 16 + lr;
        bfr[ct] = *(const bf16x8*)(Bs + c * 64 + (((ks * 4 + ls) ^ (c & 7)) * 8));
      }
      #pragma unroll
      for (int rt = 0; rt < 2; ++rt)
        #pragma unroll
        for (int ct = 0; ct < 4; ++ct)
          acc[rt][ct] = MFMA(af[rt], bfr[ct], acc[rt][ct]);
    }
  }
  __syncthreads();  // all waves done reading Bs before Cs overlays it
  // epilogue: + bias -> Cs -> coalesced bf16x8 stores
  #pragma unroll
  for (int ct = 0; ct < 4; ++ct) {
    float b = qkv_b[nb * 128 + wc * 64 + ct * 16 + lr];
    #pragma unroll
    for (int rt = 0; rt < 2; ++rt)
      #pragma unroll
      for (int r = 0; r < 4; ++r) {
        int row = wr * 32 + rt * 16 + ls * 4 + r;
        Cs[row * 128 + wc * 64 + ct * 16 + lr] = (__bf16)(acc[rt][ct][r] + b);
      }
  }
  __syncthreads();
  #pragma unroll
  for (int j = 0; j < 4; ++j) {
    int p = j * 256 + t;
    int row = p >> 4, sub = p & 15;
    *(bf16x8*)(qkv + (size_t)(mb * 64 + row) * 1152 + nb * 128 + sub * 8) =
        *(const bf16x8*)(Cs + p * 8);
  }
}

// ---------------- K2a: attention, one wave per (window, head) ----------------
// 24576 independent waves, no barriers. V staged in wave-private LDS (vector
// loads, chunk-XOR swizzle). Softmax: no max-sub (bounded), denom via ones-MFMA.
// H written into the Q-slice of qkv (owned by this (w,h)).
__global__ __launch_bounds__(256, 3) void wa_attn(
    const float* __restrict__ biasTt, __bf16* __restrict__ qkv) {
  __shared__ __bf16 Pbuf[4][4096];  // 8KB/wave
  __shared__ __bf16 Vbuf[4][2048];  // 4KB/wave
  const int t = threadIdx.x, lane = t & 63, wv = t >> 6;
  const int lr = lane & 15, ls = lane >> 4;
  const int pair = blockIdx.x * 4 + wv;     // 0..24575
  const int w = pair / NH, h = pair - w * NH;
  const int w49 = w * 49;
  __bf16* Pw = Pbuf[wv];
  __bf16* Vw = Vbuf[wv];
  f32x4 zero = {0.f, 0.f, 0.f, 0.f};
  bf16x8 ones;
  #pragma unroll
  for (int e = 0; e < 8; ++e) ones[e] = (__bf16)1.0f;

  // stage V: lane = row j (rows>=49 clamp to 48: finite, killed by P=0)
  {
    int row = lane;
    int tok = w49 + (row < 49 ? row : 48);
    const bf16x8* vsrc = (const bf16x8*)(qkv + (size_t)tok * 1152 + 768 + h * 32);
    int f = (row & 3) ^ ((row >> 3) & 3);
    #pragma unroll
    for (int c = 0; c < 4; ++c)
      *(bf16x8*)(Vw + row * 32 + ((c ^ f) * 8)) = vsrc[c];
  }
  // Q,K fragments direct from global (full 64B lines per 16 rows)
  bf16x8 qa[4], kb[4];
  #pragma unroll
  for (int rt = 0; rt < 4; ++rt) {
    int tok = min(w49 + rt * 16 + lr, TOKENS - 1);
    qa[rt] = *(const bf16x8*)(qkv + (size_t)tok * 1152 + h * 32 + ls * 8);
  }
  #pragma unroll
  for (int ct = 0; ct < 4; ++ct) {
    int tok = min(w49 + ct * 16 + lr, TOKENS - 1);
    kb[ct] = *(const bf16x8*)(qkv + (size_t)tok * 1152 + 384 + h * 32 + ls * 8);
  }
  f32x4 sacc[4][4];
  #pragma unroll
  for (int rt = 0; rt < 4; ++rt)
    #pragma unroll
    for (int ct = 0; ct < 4; ++ct)
      sacc[rt][ct] = MFMA(qa[rt], kb[ct], zero);
  // scale + bias + exp -> swizzled Pbuf (unnormalized probs; masked cols -> 0)
  #pragma unroll
  for (int rt = 0; rt < 4; ++rt) {
    int row0 = rt * 16 + ls * 4;
    #pragma unroll
    for (int ct = 0; ct < 4; ++ct) {
      int col = ct * 16 + lr;
      float4 bias = *(const float4*)(biasTt + (size_t)(h * 64 + col) * 64 + row0);
      #pragma unroll
      for (int r = 0; r < 4; ++r) {
        int row = row0 + r;
        float pr = __expf(fmaf(sacc[rt][ct][r], SCALE, ((const float*)&bias)[r]));
        Pw[row * 64 + (((col >> 3) ^ (row & 7)) * 8) + (col & 7)] = (__bf16)pr;
      }
    }
  }
  // PV + row sums (ones trick); V^T frags from LDS (swizzled scalar reads)
  f32x4 oacc[4][2] = {};
  f32x4 osum[4] = {zero, zero, zero, zero};
  #pragma unroll
  for (int ks = 0; ks < 2; ++ks) {
    bf16x8 vb0, vb1;
    #pragma unroll
    for (int e = 0; e < 8; ++e) {
      int j = ks * 32 + ls * 8 + e;
      int a = j * 32 + (((lr >> 3) ^ (e & 3) ^ ls) * 8) + (lr & 7);
      vb0[e] = Vw[a];
      vb1[e] = Vw[a ^ 16];
    }
    #pragma unroll
    for (int rt = 0; rt < 4; ++rt) {
      int row = rt * 16 + lr;
      bf16x8 pa = *(const bf16x8*)(Pw + row * 64 + (((ks * 4 + ls) ^ (row & 7)) * 8));
      oacc[rt][0] = MFMA(pa, vb0, oacc[rt][0]);
      oacc[rt][1] = MFMA(pa, vb1, oacc[rt][1]);
      osum[rt]    = MFMA(pa, ones, osum[rt]);
    }
  }
  // normalize + write H into Q slice (rows < 49 only)
  #pragma unroll
  for (int rt = 0; rt < 4; ++rt)
    #pragma unroll
    for (int r = 0; r < 4; ++r) {
      int row = rt * 16 + ls * 4 + r;
      if (row < 49) {
        float inv = 1.0f / osum[rt][r];
        __bf16* o = qkv + (size_t)(w49 + row) * 1152 + h * 32;
        o[lr]      = (__bf16)(oacc[rt][0][r] * inv);
        o[16 + lr] = (__bf16)(oacc[rt][1][r] * inv);
      }
    }
}

// ---------------- K2b: proj GEMM 64x128, BK=64, 6 blocks/CU ----------------
// A = H (bf16, qkv cols 0..383) via gload_lds; 24KB LDS, launch_bounds(256,6)
// -> 6 blocks/CU. Grid 4704 XCD-grouped (3 nb-blocks per mb).
__global__ __launch_bounds__(256, 6) void wa_proj(
    const __bf16* __restrict__ qkv, const __bf16* __restrict__ pw,
    const float* __restrict__ proj_b, float* __restrict__ out) {
  __shared__ alignas(16) __bf16 As[64 * 64];    // 8KB
  __shared__ alignas(16) __bf16 Bs[128 * 64];   // 16KB
  const int t = threadIdx.x, lane = t & 63, wv = t >> 6;
  const int lr = lane & 15, ls = lane >> 4;
  const int bid = blockIdx.x;
  const int q = bid / 24, rem = bid - q * 24;
  const int nb = rem >> 3, mb = q * 8 + (rem & 7);
  const int wr = wv >> 1, wc = wv & 1;
  f32x4 acc[2][4] = {};
  for (int kk = 0; kk < 6; ++kk) {
    if (kk) __syncthreads();
    #pragma unroll
    for (int j = 0; j < 2; ++j) {  // A tile via gload_lds, source pre-swizzled
      int p = j * 256 + t;
      int row = p >> 3, sl = p & 7;
      gload_lds16(qkv + (size_t)(mb * 64 + row) * 1152 + kk * 64 + (sl ^ (row & 7)) * 8,
                  As + p * 8);
    }
    #pragma unroll
    for (int j = 0; j < 4; ++j) {
      int p = j * 256 + t;
      int c = p >> 3, sl = p & 7;
      gload_lds16(pw + (size_t)(nb * 128 + c) * 384 + kk * 64 + (sl ^ (c & 7)) * 8,
                  Bs + p * 8);
    }
    __syncthreads();
    #pragma unroll
    for (int ks = 0; ks < 2; ++ks) {
      bf16x8 af[2], bfr[4];
      #pragma unroll
      for (int rt = 0; rt < 2; ++rt) {
        int row = wr * 32 + rt * 16 + lr;
        af[rt] = *(const bf16x8*)(As + row * 64 + (((ks * 4 + ls) ^ (row & 7)) * 8));
      }
      #pragma unroll
      for (int ct = 0; ct < 4; ++ct) {
        int c = wc * 64 + ct * 16 + lr;
        bfr[ct] = *(const bf16x8*)(Bs + c * 64 + (((ks * 4 + ls) ^ (c & 7)) * 8));
      }
      #pragma unroll
      for (int rt = 0; rt < 2; ++rt)
        #pragma unroll
        for (int ct = 0; ct < 4; ++ct)
          acc[rt][ct] = MFMA(af[rt], bfr[ct], acc[rt][ct]);
    }
  }
  // epilogue: fp32 direct stores (16-lane 64B runs) + bias
  #pragma unroll
  for (int ct = 0; ct < 4; ++ct) {
    int col = nb * 128 + wc * 64 + ct * 16 + lr;
    float b = proj_b[col];
    #pragma unroll
    for (int rt = 0; rt < 2; ++rt)
      #pragma unroll
      for (int r = 0; r < 4; ++r) {
        int row = wr * 32 + rt * 16 + ls * 4 + r;
        out[(size_t)(mb * 64 + row) * 384 + col] = acc[rt][ct][r] + b;
      }
  }
}

extern "C" void kernel_launch(void* const* d_in, const int* in_sizes, int n_in,
                              void* d_out, int out_size, void* d_ws, size_t ws_size,
                              hipStream_t stream) {
  const float* x      = (const float*)d_in[0];
  const float* qkv_w  = (const float*)d_in[1];
  const float* qkv_b  = (const float*)d_in[2];
  const float* proj_w = (const float*)d_in[3];
  const float* proj_b = (const float*)d_in[4];
  const float* tbl    = (const float*)d_in[5];
  float* out = (float*)d_out;

  char* ws = (char*)d_ws;
  __bf16* qkv_w_bf  = (__bf16*)ws;                  // 884,736 B
  __bf16* proj_w_bf = (__bf16*)(ws + 884736);       // 294,912 B
  float*  biasTt    = (float*)(ws + 1179648);       // 196,608 B
  __bf16* qkv_buf   = (__bf16*)(ws + 1376256);      // 231,211,008 B

  wa_prep<<<2496, 256, 0, stream>>>(qkv_w, proj_w, tbl, qkv_w_bf, proj_w_bf, biasTt);
  wa_qkv<<<14112, 256, 0, stream>>>(x, qkv_w_bf, qkv_b, qkv_buf);
  wa_attn<<<6144, 256, 0, stream>>>(biasTt, qkv_buf);
  wa_proj<<<4704, 256, 0, stream>>>(qkv_buf, proj_w_bf, proj_b, out);
}

// Round 10
// 327.338 us; speedup vs baseline: 1.2537x; 1.2537x over previous
//
#include <hip/hip_runtime.h>
#include <hip/hip_bf16.h>

#define NH 12
constexpr float SCALE = 0.17677669529663687f;  // 1/sqrt(32)
constexpr int TOKENS = 100352;

using f32x4  = __attribute__((ext_vector_type(4))) float;
using bf16x8 = __attribute__((ext_vector_type(8))) __bf16;

__device__ inline void gload_lds16(const void* g, void* l) {
  __builtin_amdgcn_global_load_lds(
      (const __attribute__((address_space(1))) void*)g,
      (__attribute__((address_space(3))) void*)l, 16, 0, 0);
}

__device__ inline bf16x8 cvt8(float4 a, float4 b) {
  bf16x8 o;
  o[0] = (__bf16)a.x; o[1] = (__bf16)a.y; o[2] = (__bf16)a.z; o[3] = (__bf16)a.w;
  o[4] = (__bf16)b.x; o[5] = (__bf16)b.y; o[6] = (__bf16)b.z; o[7] = (__bf16)b.w;
  return o;
}

#define MFMA(a, b, c) __builtin_amdgcn_mfma_f32_16x16x32_bf16(a, b, c, 0, 0, 0)

// ---------------- K0: weight bf16 conversion + transposed padded bias ----------
// biasTt layout: [12][64 col(j)][64 row(i)] fp32; j>=49 -> -1e30 (mask), i>=49 -> 0.
__global__ __launch_bounds__(256) void wa_prep(
    const float* __restrict__ qkv_w, const float* __restrict__ proj_w,
    const float* __restrict__ tbl,
    __bf16* __restrict__ qkv_w_bf, __bf16* __restrict__ proj_w_bf,
    float* __restrict__ biasTt) {
  int p = blockIdx.x * 256 + threadIdx.x;
  if (p < 442368) { qkv_w_bf[p] = (__bf16)qkv_w[p]; return; }
  p -= 442368;
  if (p < 147456) { proj_w_bf[p] = (__bf16)proj_w[p]; return; }
  p -= 147456;
  if (p >= 49152) return;
  int h = p >> 12, rem = p & 4095, j = rem >> 6, i = rem & 63;  // j=key col, i=query row
  float v;
  if (j >= 49) v = -1e30f;
  else if (i >= 49) v = 0.0f;
  else {
    int py = i / 7, px = i % 7, qy = j / 7, qx = j % 7;
    v = tbl[((py - qy + 6) * 13 + (px - qx + 6)) * NH + h];
  }
  biasTt[p] = v;
}

// ---------------- K1: QKV GEMM 64x128, BK=64, 24KB LDS ----------------
// LDS 24KB (Cs overlays Bs) -> HW can fit 6 blocks/CU; launch_bounds(256,4)
// keeps VGPR budget at 128 so regalloc does NOT spill (round-9's (256,6)
// capped VGPR at 40 -> 240MB of scratch traffic, 204->267us regression).
// Grid 14112 XCD-grouped: the 9 nb-blocks of one mb land on one XCD.
__global__ __launch_bounds__(256, 4) void wa_qkv(
    const float* __restrict__ x, const __bf16* __restrict__ wq,
    const float* __restrict__ qkv_b, __bf16* __restrict__ qkv) {
  __shared__ alignas(16) __bf16 smem[12288];   // 24KB
  __bf16* As = smem;          // [64 rows][8 chunks ^ (row&7)]  8KB
  __bf16* Bs = smem + 4096;   // [128 cols][8 chunks ^ (col&7)] 16KB
  __bf16* Cs = smem + 4096;   // overlays Bs (epilogue only)
  const int t = threadIdx.x, lane = t & 63, wv = t >> 6;
  const int lr = lane & 15, ls = lane >> 4;
  const int bid = blockIdx.x;
  const int q = bid / 72, rem = bid - q * 72;
  const int nb = rem >> 3, mb = q * 8 + (rem & 7);
  const int wr = wv >> 1, wc = wv & 1;   // wave tile: 32 rows x 64 cols
  f32x4 acc[2][4] = {};
  for (int kk = 0; kk < 6; ++kk) {
    if (kk) __syncthreads();
    // issue A fp32 loads (2 chunks/thread) + B gload_lds (4/thread)
    float4 a0[2], a1[2];
    int rowA[2], cA[2];
    #pragma unroll
    for (int j = 0; j < 2; ++j) {
      int p = j * 256 + t;
      rowA[j] = p >> 3; cA[j] = p & 7;
      const float* src = x + (size_t)(mb * 64 + rowA[j]) * 384 + kk * 64 + cA[j] * 8;
      a0[j] = *(const float4*)src;
      a1[j] = *(const float4*)(src + 4);
    }
    #pragma unroll
    for (int j = 0; j < 4; ++j) {
      int p = j * 256 + t;
      int c = p >> 3, sl = p & 7;
      gload_lds16(wq + (size_t)(nb * 128 + c) * 384 + kk * 64 + (sl ^ (c & 7)) * 8,
                  Bs + p * 8);
    }
    #pragma unroll
    for (int j = 0; j < 2; ++j) {
      int cw = cA[j] ^ (rowA[j] & 7);
      *(bf16x8*)(As + rowA[j] * 64 + cw * 8) = cvt8(a0[j], a1[j]);
    }
    __syncthreads();
    #pragma unroll
    for (int ks = 0; ks < 2; ++ks) {
      bf16x8 af[2], bfr[4];
      #pragma unroll
      for (int rt = 0; rt < 2; ++rt) {
        int row = wr * 32 + rt * 16 + lr;
        af[rt] = *(const bf16x8*)(As + row * 64 + (((ks * 4 + ls) ^ (row & 7)) * 8));
      }
      #pragma unroll
      for (int ct = 0; ct < 4; ++ct) {
        int c = wc * 64 + ct * 16 + lr;
        bfr[ct] = *(const bf16x8*)(Bs + c * 64 + (((ks * 4 + ls) ^ (c & 7)) * 8));
      }
      #pragma unroll
      for (int rt = 0; rt < 2; ++rt)
        #pragma unroll
        for (int ct = 0; ct < 4; ++ct)
          acc[rt][ct] = MFMA(af[rt], bfr[ct], acc[rt][ct]);
    }
  }
  __syncthreads();  // all waves done reading Bs before Cs overlays it
  // epilogue: + bias -> Cs -> coalesced bf16x8 stores
  #pragma unroll
  for (int ct = 0; ct < 4; ++ct) {
    float b = qkv_b[nb * 128 + wc * 64 + ct * 16 + lr];
    #pragma unroll
    for (int rt = 0; rt < 2; ++rt)
      #pragma unroll
      for (int r = 0; r < 4; ++r) {
        int row = wr * 32 + rt * 16 + ls * 4 + r;
        Cs[row * 128 + wc * 64 + ct * 16 + lr] = (__bf16)(acc[rt][ct][r] + b);
      }
  }
  __syncthreads();
  #pragma unroll
  for (int j = 0; j < 4; ++j) {
    int p = j * 256 + t;
    int row = p >> 4, sub = p & 15;
    *(bf16x8*)(qkv + (size_t)(mb * 64 + row) * 1152 + nb * 128 + sub * 8) =
        *(const bf16x8*)(Cs + p * 8);
  }
}

// ---------------- K2a: attention, one wave per (window, head) ----------------
// 24576 independent waves, no barriers. V staged in wave-private LDS (vector
// loads, chunk-XOR swizzle). Softmax: no max-sub (bounded), denom via ones-MFMA.
// H written into the Q-slice of qkv (owned by this (w,h)).
__global__ __launch_bounds__(256, 3) void wa_attn(
    const float* __restrict__ biasTt, __bf16* __restrict__ qkv) {
  __shared__ __bf16 Pbuf[4][4096];  // 8KB/wave
  __shared__ __bf16 Vbuf[4][2048];  // 4KB/wave
  const int t = threadIdx.x, lane = t & 63, wv = t >> 6;
  const int lr = lane & 15, ls = lane >> 4;
  const int pair = blockIdx.x * 4 + wv;     // 0..24575
  const int w = pair / NH, h = pair - w * NH;
  const int w49 = w * 49;
  __bf16* Pw = Pbuf[wv];
  __bf16* Vw = Vbuf[wv];
  f32x4 zero = {0.f, 0.f, 0.f, 0.f};
  bf16x8 ones;
  #pragma unroll
  for (int e = 0; e < 8; ++e) ones[e] = (__bf16)1.0f;

  // stage V: lane = row j (rows>=49 clamp to 48: finite, killed by P=0)
  {
    int row = lane;
    int tok = w49 + (row < 49 ? row : 48);
    const bf16x8* vsrc = (const bf16x8*)(qkv + (size_t)tok * 1152 + 768 + h * 32);
    int f = (row & 3) ^ ((row >> 3) & 3);
    #pragma unroll
    for (int c = 0; c < 4; ++c)
      *(bf16x8*)(Vw + row * 32 + ((c ^ f) * 8)) = vsrc[c];
  }
  // Q,K fragments direct from global (full 64B lines per 16 rows)
  bf16x8 qa[4], kb[4];
  #pragma unroll
  for (int rt = 0; rt < 4; ++rt) {
    int tok = min(w49 + rt * 16 + lr, TOKENS - 1);
    qa[rt] = *(const bf16x8*)(qkv + (size_t)tok * 1152 + h * 32 + ls * 8);
  }
  #pragma unroll
  for (int ct = 0; ct < 4; ++ct) {
    int tok = min(w49 + ct * 16 + lr, TOKENS - 1);
    kb[ct] = *(const bf16x8*)(qkv + (size_t)tok * 1152 + 384 + h * 32 + ls * 8);
  }
  f32x4 sacc[4][4];
  #pragma unroll
  for (int rt = 0; rt < 4; ++rt)
    #pragma unroll
    for (int ct = 0; ct < 4; ++ct)
      sacc[rt][ct] = MFMA(qa[rt], kb[ct], zero);
  // scale + bias + exp -> swizzled Pbuf (unnormalized probs; masked cols -> 0)
  #pragma unroll
  for (int rt = 0; rt < 4; ++rt) {
    int row0 = rt * 16 + ls * 4;
    #pragma unroll
    for (int ct = 0; ct < 4; ++ct) {
      int col = ct * 16 + lr;
      float4 bias = *(const float4*)(biasTt + (size_t)(h * 64 + col) * 64 + row0);
      #pragma unroll
      for (int r = 0; r < 4; ++r) {
        int row = row0 + r;
        float pr = __expf(fmaf(sacc[rt][ct][r], SCALE, ((const float*)&bias)[r]));
        Pw[row * 64 + (((col >> 3) ^ (row & 7)) * 8) + (col & 7)] = (__bf16)pr;
      }
    }
  }
  // PV + row sums (ones trick); V^T frags from LDS (swizzled scalar reads)
  f32x4 oacc[4][2] = {};
  f32x4 osum[4] = {zero, zero, zero, zero};
  #pragma unroll
  for (int ks = 0; ks < 2; ++ks) {
    bf16x8 vb0, vb1;
    #pragma unroll
    for (int e = 0; e < 8; ++e) {
      int j = ks * 32 + ls * 8 + e;
      int a = j * 32 + (((lr >> 3) ^ (e & 3) ^ ls) * 8) + (lr & 7);
      vb0[e] = Vw[a];
      vb1[e] = Vw[a ^ 16];
    }
    #pragma unroll
    for (int rt = 0; rt < 4; ++rt) {
      int row = rt * 16 + lr;
      bf16x8 pa = *(const bf16x8*)(Pw + row * 64 + (((ks * 4 + ls) ^ (row & 7)) * 8));
      oacc[rt][0] = MFMA(pa, vb0, oacc[rt][0]);
      oacc[rt][1] = MFMA(pa, vb1, oacc[rt][1]);
      osum[rt]    = MFMA(pa, ones, osum[rt]);
    }
  }
  // normalize + write H into Q slice (rows < 49 only)
  #pragma unroll
  for (int rt = 0; rt < 4; ++rt)
    #pragma unroll
    for (int r = 0; r < 4; ++r) {
      int row = rt * 16 + ls * 4 + r;
      if (row < 49) {
        float inv = 1.0f / osum[rt][r];
        __bf16* o = qkv + (size_t)(w49 + row) * 1152 + h * 32;
        o[lr]      = (__bf16)(oacc[rt][0][r] * inv);
        o[16 + lr] = (__bf16)(oacc[rt][1][r] * inv);
      }
    }
}

// ---------------- K2b: proj GEMM 64x128, BK=64 ----------------
// A = H (bf16, qkv cols 0..383) via gload_lds; 24KB LDS; launch_bounds(256,4)
// (VGPR budget 128, no spill) -> HW fits 6 blocks/CU via LDS cap.
__global__ __launch_bounds__(256, 4) void wa_proj(
    const __bf16* __restrict__ qkv, const __bf16* __restrict__ pw,
    const float* __restrict__ proj_b, float* __restrict__ out) {
  __shared__ alignas(16) __bf16 As[64 * 64];    // 8KB
  __shared__ alignas(16) __bf16 Bs[128 * 64];   // 16KB
  const int t = threadIdx.x, lane = t & 63, wv = t >> 6;
  const int lr = lane & 15, ls = lane >> 4;
  const int bid = blockIdx.x;
  const int q = bid / 24, rem = bid - q * 24;
  const int nb = rem >> 3, mb = q * 8 + (rem & 7);
  const int wr = wv >> 1, wc = wv & 1;
  f32x4 acc[2][4] = {};
  for (int kk = 0; kk < 6; ++kk) {
    if (kk) __syncthreads();
    #pragma unroll
    for (int j = 0; j < 2; ++j) {  // A tile via gload_lds, source pre-swizzled
      int p = j * 256 + t;
      int row = p >> 3, sl = p & 7;
      gload_lds16(qkv + (size_t)(mb * 64 + row) * 1152 + kk * 64 + (sl ^ (row & 7)) * 8,
                  As + p * 8);
    }
    #pragma unroll
    for (int j = 0; j < 4; ++j) {
      int p = j * 256 + t;
      int c = p >> 3, sl = p & 7;
      gload_lds16(pw + (size_t)(nb * 128 + c) * 384 + kk * 64 + (sl ^ (c & 7)) * 8,
                  Bs + p * 8);
    }
    __syncthreads();
    #pragma unroll
    for (int ks = 0; ks < 2; ++ks) {
      bf16x8 af[2], bfr[4];
      #pragma unroll
      for (int rt = 0; rt < 2; ++rt) {
        int row = wr * 32 + rt * 16 + lr;
        af[rt] = *(const bf16x8*)(As + row * 64 + (((ks * 4 + ls) ^ (row & 7)) * 8));
      }
      #pragma unroll
      for (int ct = 0; ct < 4; ++ct) {
        int c = wc * 64 + ct * 16 + lr;
        bfr[ct] = *(const bf16x8*)(Bs + c * 64 + (((ks * 4 + ls) ^ (c & 7)) * 8));
      }
      #pragma unroll
      for (int rt = 0; rt < 2; ++rt)
        #pragma unroll
        for (int ct = 0; ct < 4; ++ct)
          acc[rt][ct] = MFMA(af[rt], bfr[ct], acc[rt][ct]);
    }
  }
  // epilogue: fp32 direct stores (16-lane 64B runs) + bias
  #pragma unroll
  for (int ct = 0; ct < 4; ++ct) {
    int col = nb * 128 + wc * 64 + ct * 16 + lr;
    float b = proj_b[col];
    #pragma unroll
    for (int rt = 0; rt < 2; ++rt)
      #pragma unroll
      for (int r = 0; r < 4; ++r) {
        int row = wr * 32 + rt * 16 + ls * 4 + r;
        out[(size_t)(mb * 64 + row) * 384 + col] = acc[rt][ct][r] + b;
      }
  }
}

extern "C" void kernel_launch(void* const* d_in, const int* in_sizes, int n_in,
                              void* d_out, int out_size, void* d_ws, size_t ws_size,
                              hipStream_t stream) {
  const float* x      = (const float*)d_in[0];
  const float* qkv_w  = (const float*)d_in[1];
  const float* qkv_b  = (const float*)d_in[2];
  const float* proj_w = (const float*)d_in[3];
  const float* proj_b = (const float*)d_in[4];
  const float* tbl    = (const float*)d_in[5];
  float* out = (float*)d_out;

  char* ws = (char*)d_ws;
  __bf16* qkv_w_bf  = (__bf16*)ws;                  // 884,736 B
  __bf16* proj_w_bf = (__bf16*)(ws + 884736);       // 294,912 B
  float*  biasTt    = (float*)(ws + 1179648);       // 196,608 B
  __bf16* qkv_buf   = (__bf16*)(ws + 1376256);      // 231,211,008 B

  wa_prep<<<2496, 256, 0, stream>>>(qkv_w, proj_w, tbl, qkv_w_bf, proj_w_bf, biasTt);
  wa_qkv<<<14112, 256, 0, stream>>>(x, qkv_w_bf, qkv_b, qkv_buf);
  wa_attn<<<6144, 256, 0, stream>>>(biasTt, qkv_buf);
  wa_proj<<<4704, 256, 0, stream>>>(qkv_buf, proj_w_bf, proj_b, out);
}